// Round 14
// baseline (132.371 us; speedup 1.0000x reference)
//
#include <hip/hip_runtime.h>
#include <hip/hip_fp16.h>

typedef float fvec4 __attribute__((ext_vector_type(4)));
typedef int ivec4 __attribute__((ext_vector_type(4)));

#define NN 65536      // total nodes per side (B*NPG)
#define EE 1048576    // edges per side (B*NPG*DEG)
#define BB 128
#define NPG 512
#define EPG 8192      // edges per graph (NPG*DEG)

__device__ __forceinline__ int pk2(float a, float b) {
  union { __half2 h; int i; } u; u.h = __floats2half2_rn(a, b); return u.i;
}
__device__ __forceinline__ float2 up2(int v) {
  union { int i; __half2 h; } u; u.i = v; return __half22float2(u.h);
}

// accumulate one 16B quad (8 f16) into two fvec4 partial sums (f32 exact)
#define ACCQ(S, w) { float2 f_; \
  f_ = up2((w)[0]); (S)[0][0] += f_.x; (S)[0][1] += f_.y; \
  f_ = up2((w)[1]); (S)[0][2] += f_.x; (S)[0][3] += f_.y; \
  f_ = up2((w)[2]); (S)[1][0] += f_.x; (S)[1][1] += f_.y; \
  f_ = up2((w)[3]); (S)[1][2] += f_.x; (S)[1][3] += f_.y; }

// ---- publish 32 floats (acc[0..7]) scaled by inv as f16 quads, swizzled ----
// line = 2 rows = 128 B; quad q of row r at slot (q + 4*(r&1) + ((r>>1)&7)) & 7.
__device__ __forceinline__ void pub32(const fvec4* acc, float inv_v, int node, ivec4* buf) {
  const int line = node >> 1;
  const int m = ((node & 1) << 2) + (line & 7);
  const int b = line << 3;
#pragma unroll
  for (int q = 0; q < 4; ++q) {
    fvec4 a0 = acc[2 * q] * inv_v;
    fvec4 a1 = acc[2 * q + 1] * inv_v;
    ivec4 w;
    w[0] = pk2(a0[0], a0[1]); w[1] = pk2(a0[2], a0[3]);
    w[2] = pk2(a1[0], a1[1]); w[3] = pk2(a1[2], a1[3]);
    buf[b | ((q + m) & 7)] = w;
  }
}

// ---------------- one block per (side, graph): CSR build + degree-sort + 3 GCN layers ----------------
// Messages in f16 (rel err ~5e-4, accumulation exact f32). sids packed keys:
// (line<<4)|m with m = ((r&1)<<2)+(line&7); decode: base = (key>>1)&~7, slot = (q+key)&7.
__global__ __launch_bounds__(512)
void k_all(const float* __restrict__ x_i, const float* __restrict__ x_j,
           const float* __restrict__ gw0, const float* __restrict__ gb0,
           const float* __restrict__ gw1, const float* __restrict__ gb1,
           const float* __restrict__ gw2, const float* __restrict__ gb2,
           const int* __restrict__ ei, const int* __restrict__ ej,
           float* __restrict__ hs0, float* __restrict__ hs1, float* __restrict__ hs2) {
  __shared__ int sids[EPG];                // 32 KB
  __shared__ ivec4 bufA[(NPG / 2) * 8];    // 32 KB f16 msg buffer A (aliases dsts in prep)
  __shared__ ivec4 bufB[(NPG / 2) * 8];    // 32 KB f16 msg buffer B
  __shared__ int cnt[NPG];
  __shared__ int posb[NPG];
  __shared__ int nodeOf[NPG];
  __shared__ int bins[64];
  __shared__ int binpos[64];
  __shared__ int wsum[8];
  int* const dsts = reinterpret_cast<int*>(bufA);  // prep-only staging

  const int side = blockIdx.x >> 7;
  const int g = blockIdx.x & 127;
  const float* __restrict__ x = side ? x_j : x_i;
  const int* __restrict__ eidx = side ? ej : ei;
  const int v = threadIdx.x;
  const int base = g * NPG;
  const int ebase = g * EPG;

  // ---- in-LDS degree count ----
  cnt[v] = 0;
  if (v < 64) bins[v] = 0;
  __syncthreads();
  for (int k = v; k < EPG; k += 512) {
    int d = eidx[EE + ebase + k] - base;
    dsts[k] = d;
    atomicAdd(&cnt[d], 1);
  }
  __syncthreads();

  // ---- scan over 512 counts + degree histogram ----
  const int count = cnt[v];
  const int deg = count > 63 ? 63 : count;
  atomicAdd(&bins[deg], 1);
  int xa = count;
  const int lane = v & 63;
#pragma unroll
  for (int d = 1; d < 64; d <<= 1) {
    int y = __shfl_up(xa, d, 64);
    if (lane >= d) xa += y;
  }
  const int wid = v >> 6;
  if (lane == 63) wsum[wid] = xa;
  __syncthreads();
  if (v < 64) {
    if (v == 0) {
      int a = 0;
#pragma unroll
      for (int i = 0; i < 8; ++i) { int tv = wsum[i]; wsum[i] = a; a += tv; }
    }
    int c = bins[v];
    int xb = c;
#pragma unroll
    for (int d = 1; d < 64; d <<= 1) {
      int y = __shfl_up(xb, d, 64);
      if (v >= d) xb += y;
    }
    binpos[v] = xb - c;
  }
  __syncthreads();
  const int start_v = xa - count + wsum[wid];
  posb[v] = start_v;
  {
    int rank = atomicAdd(&binpos[deg], 1);
    nodeOf[rank] = v;
  }
  __syncthreads();

  // ---- CSR fill with packed swizzle keys ----
  for (int k = v; k < EPG; k += 512) {
    int lv = eidx[ebase + k] - base;
    int p = atomicAdd(&posb[dsts[k]], 1);
    int line = lv >> 1;
    int m = ((lv & 1) << 2) + (line & 7);
    sids[p] = (line << 4) | m;
  }
  __syncthreads();

  // ---- this thread owns node = nodeOf[v] (wave-uniform degrees) ----
  const int node = nodeOf[v];
  const int ncount = cnt[node];
  const int nstart = posb[node] - ncount;
  const float inv_v = rsqrtf((float)ncount + 1.0f);

  constexpr int srows[20] = {25, 26, 76, 77, 127, 128, 178, 179, 229, 230,
                             281, 282, 332, 333, 383, 384, 434, 435, 485, 486};
  int slot = -1;
#pragma unroll
  for (int i = 0; i < 20; ++i)
    if (node == srows[i]) slot = i;
  const int hb = (side * BB + g) * 20;

  // ---- layer 0: full xW0 row in one streaming pass over x ----
  fvec4 a0[16];
#pragma unroll
  for (int q = 0; q < 16; ++q) a0[q] = fvec4{0.f, 0.f, 0.f, 0.f};
  {
    const fvec4* xv = reinterpret_cast<const fvec4*>(x + (size_t)(base + node) * 64);
#pragma unroll 1
    for (int k16 = 0; k16 < 4; ++k16) {
      fvec4 xq[4];
#pragma unroll
      for (int u = 0; u < 4; ++u) xq[u] = xv[4 * k16 + u];
#pragma unroll
      for (int u = 0; u < 4; ++u) {
#pragma unroll
        for (int j = 0; j < 4; ++j) {
          const float xk = xq[u][j];
          const fvec4* wr = reinterpret_cast<const fvec4*>(gw0 + (size_t)(16 * k16 + 4 * u + j) * 64);
#pragma unroll
          for (int q = 0; q < 16; ++q) a0[q] += xk * wr[q];
        }
      }
    }
  }

  // ---- L0: publish both 32-wide halves (f16), init s with own msg, a0 dies ----
  pub32(&a0[0], inv_v, node, bufA);
  pub32(&a0[8], inv_v, node, bufB);
  fvec4 sA[8], sB[8];
#pragma unroll
  for (int q = 0; q < 8; ++q) { sA[q] = a0[q] * inv_v; sB[q] = a0[8 + q] * inv_v; }
  __syncthreads();

  // ---- L0 merged gather (A and B in one edge loop) ----
  {
    const int end = nstart + ncount;
    for (int e = nstart; e < end; ++e) {
      const int key = sids[e];
      const int b = (key >> 1) & ~7;
#pragma unroll
      for (int q = 0; q < 4; ++q) {
        const int idx = b | ((q + key) & 7);
        const ivec4 wa = bufA[idx];
        const ivec4 wb = bufB[idx];
        ACCQ((&sA[2 * q]), wa)
        ACCQ((&sB[2 * q]), wb)
      }
    }
  }

  // ---- L0 epilogue: h0 = relu(s*inv + b0); fold y1 = h0*W1; hs0 ----
  fvec4 y1[8];
#pragma unroll
  for (int p = 0; p < 8; ++p) y1[p] = fvec4{0.f, 0.f, 0.f, 0.f};
  {
    const fvec4* gb0v = reinterpret_cast<const fvec4*>(gb0);
    fvec4* hp = reinterpret_cast<fvec4*>(hs0 + ((size_t)hb + slot) * 64);
#pragma unroll
    for (int q = 0; q < 16; ++q) {
      fvec4 s = (q < 8) ? sA[q] : sB[q - 8];
      fvec4 o = s * inv_v + gb0v[q];
#pragma unroll
      for (int j = 0; j < 4; ++j) o[j] = fmaxf(o[j], 0.f);
      if (slot >= 0) hp[q] = o;
#pragma unroll
      for (int j = 0; j < 4; ++j) {
        const float hf = o[j];
        const fvec4* wr = reinterpret_cast<const fvec4*>(gw1 + (size_t)(q * 4 + j) * 32);
#pragma unroll
        for (int p = 0; p < 8; ++p) y1[p] += hf * wr[p];
      }
    }
  }
  __syncthreads();  // all L0 reads of bufA done

  // ---- L1: publish y1 (f16) into A, gather, fold y2 ----
  pub32(y1, inv_v, node, bufA);
  fvec4 s1[8];
#pragma unroll
  for (int q = 0; q < 8; ++q) s1[q] = y1[q] * inv_v;
  __syncthreads();
  {
    const int end = nstart + ncount;
    for (int e = nstart; e < end; ++e) {
      const int key = sids[e];
      const int b = (key >> 1) & ~7;
#pragma unroll
      for (int q = 0; q < 4; ++q) {
        const ivec4 w = bufA[b | ((q + key) & 7)];
        ACCQ((&s1[2 * q]), w)
      }
    }
  }
  fvec4 y2[4];
#pragma unroll
  for (int p = 0; p < 4; ++p) y2[p] = fvec4{0.f, 0.f, 0.f, 0.f};
  {
    const fvec4* gb1v = reinterpret_cast<const fvec4*>(gb1);
    fvec4* hp = reinterpret_cast<fvec4*>(hs1 + ((size_t)hb + slot) * 32);
#pragma unroll
    for (int q = 0; q < 8; ++q) {
      fvec4 o = s1[q] * inv_v + gb1v[q];
#pragma unroll
      for (int j = 0; j < 4; ++j) o[j] = fmaxf(o[j], 0.f);
      if (slot >= 0) hp[q] = o;
#pragma unroll
      for (int j = 0; j < 4; ++j) {
        const float hf = o[j];
        const fvec4* wr = reinterpret_cast<const fvec4*>(gw2 + (size_t)(q * 4 + j) * 16);
#pragma unroll
        for (int p = 0; p < 4; ++p) y2[p] += hf * wr[p];
      }
    }
  }

  // ---- L2: publish y2 (16 f16 = 2 quads) into B (disjoint from A; safe now) ----
  {
    const int line = node >> 1;
    const int m = ((node & 1) << 2) + (line & 7);
    const int b = line << 3;
    fvec4 q0 = y2[0] * inv_v, q1 = y2[1] * inv_v, q2 = y2[2] * inv_v, q3 = y2[3] * inv_v;
    ivec4 w0, w1;
    w0[0] = pk2(q0[0], q0[1]); w0[1] = pk2(q0[2], q0[3]);
    w0[2] = pk2(q1[0], q1[1]); w0[3] = pk2(q1[2], q1[3]);
    w1[0] = pk2(q2[0], q2[1]); w1[1] = pk2(q2[2], q2[3]);
    w1[2] = pk2(q3[0], q3[1]); w1[3] = pk2(q3[2], q3[3]);
    bufB[b | (m & 7)] = w0;
    bufB[b | ((1 + m) & 7)] = w1;
  }
  fvec4 s2[4];
#pragma unroll
  for (int q = 0; q < 4; ++q) s2[q] = y2[q] * inv_v;
  __syncthreads();
  if (slot >= 0) {
    const int end = nstart + ncount;
    for (int e = nstart; e < end; ++e) {
      const int key = sids[e];
      const int b = (key >> 1) & ~7;
      const ivec4 w0 = bufB[b | (key & 7)];
      const ivec4 w1 = bufB[b | ((1 + key) & 7)];
      ACCQ((&s2[0]), w0)
      ACCQ((&s2[2]), w1)
    }
    const fvec4* gb2v = reinterpret_cast<const fvec4*>(gb2);
    fvec4* hp = reinterpret_cast<fvec4*>(hs2 + ((size_t)hb + slot) * 16);
#pragma unroll
    for (int q = 0; q < 4; ++q) hp[q] = s2[q] * inv_v + gb2v[q];
  }
}

// ---------------- head: sampled sim -> bilinear 10x10 -> conv3x3(1->8) -> MLP -> sigmoid ----------------
__global__ __launch_bounds__(256) void k_head(const float* __restrict__ hs0, const float* __restrict__ hs1,
                                              const float* __restrict__ hs2,
                                              const float* __restrict__ cw0, const float* __restrict__ cb0,
                                              const float* __restrict__ cw1, const float* __restrict__ cb1,
                                              const float* __restrict__ cw2, const float* __restrict__ cb2,
                                              const float* __restrict__ mw0, const float* __restrict__ mb0,
                                              const float* __restrict__ mw1, const float* __restrict__ mb1,
                                              const float* __restrict__ mw2, const float* __restrict__ mb2,
                                              const float* __restrict__ mw3, const float* __restrict__ mb3,
                                              const float* __restrict__ mw4, const float* __restrict__ mb4,
                                              const float* __restrict__ sw, const float* __restrict__ sb,
                                              float* __restrict__ out) {
  __shared__ float hi[2240];  // 20*64 + 20*32 + 20*16
  __shared__ float hj[2240];
  __shared__ float sim[400];
  __shared__ float simr[100];
  __shared__ float feat[2400];
  __shared__ float red[256];
  __shared__ float mbuf[60];
  const int b = blockIdx.x, t = threadIdx.x;

  for (int k = t; k < 1280; k += 256) {
    hi[k] = hs0[(size_t)(0 * BB + b) * 1280 + k];
    hj[k] = hs0[(size_t)(1 * BB + b) * 1280 + k];
  }
  for (int k = t; k < 640; k += 256) {
    hi[1280 + k] = hs1[(size_t)(0 * BB + b) * 640 + k];
    hj[1280 + k] = hs1[(size_t)(1 * BB + b) * 640 + k];
  }
  for (int k = t; k < 320; k += 256) {
    hi[1920 + k] = hs2[(size_t)(0 * BB + b) * 320 + k];
    hj[1920 + k] = hs2[(size_t)(1 * BB + b) * 320 + k];
  }
  __syncthreads();

  const int Fs[3] = {64, 32, 16};
  const int HOFF[3] = {0, 1280, 1920};
  const float* CW[3] = {cw0, cw1, cw2};
  const float* CB[3] = {cb0, cb1, cb2};

  for (int li = 0; li < 3; ++li) {
    const int F = Fs[li];
    const float* Hi = hi + HOFF[li];
    const float* Hj = hj + HOFF[li];
    for (int p = t; p < 400; p += 256) {
      int r = p / 20, cq = p % 20;
      float a = 0.0f;
      for (int d = 0; d < F; ++d) a += Hi[r * F + d] * Hj[cq * F + d];
      sim[p] = a;
    }
    __syncthreads();
    if (t < 100) {
      int oy = t / 10, ox = t % 10;
      float cy = (oy + 0.5f) * (512.0f / 10.0f) - 0.5f;
      float cx = (ox + 0.5f) * (512.0f / 10.0f) - 0.5f;
      float fy = cy - floorf(cy);
      float fx = cx - floorf(cx);
      int r0 = 2 * oy, c0 = 2 * ox;
      float s00 = sim[r0 * 20 + c0], s01 = sim[r0 * 20 + c0 + 1];
      float s10 = sim[(r0 + 1) * 20 + c0], s11 = sim[(r0 + 1) * 20 + c0 + 1];
      simr[t] = (1.0f - fy) * ((1.0f - fx) * s00 + fx * s01) + fy * ((1.0f - fx) * s10 + fx * s11);
    }
    __syncthreads();
    const float* cw = CW[li];
    const float* cb = CB[li];
    for (int idx = t; idx < 800; idx += 256) {
      int cch = idx / 100, rem = idx % 100, y = rem / 10, x = rem % 10;
      float a = cb[cch];
#pragma unroll
      for (int ky = 0; ky < 3; ++ky) {
#pragma unroll
        for (int kx = 0; kx < 3; ++kx) {
          int iy = y + ky - 1, ix = x + kx - 1;
          if (iy >= 0 && iy < 10 && ix >= 0 && ix < 10)
            a += cw[cch * 9 + ky * 3 + kx] * simr[iy * 10 + ix];
        }
      }
      feat[li * 800 + idx] = fmaxf(a, 0.0f);
    }
    __syncthreads();
  }

  // MLP0: 2400 -> 32, 8 partial sums per output
  {
    int f = t & 31, part = t >> 5;
    float a = 0.0f;
    int k0 = part * 300;
    for (int k = k0; k < k0 + 300; ++k) a += feat[k] * mw0[k * 32 + f];
    red[t] = a;
    __syncthreads();
    if (t < 32) {
      float s = mb0[t];
#pragma unroll
      for (int p = 0; p < 8; ++p) s += red[p * 32 + t];
      mbuf[t] = fmaxf(s, 0.0f);
    }
    __syncthreads();
  }
  if (t < 16) {
    float s = mb1[t];
    for (int k = 0; k < 32; ++k) s += mbuf[k] * mw1[k * 16 + t];
    mbuf[32 + t] = fmaxf(s, 0.0f);
  }
  __syncthreads();
  if (t < 8) {
    float s = mb2[t];
    for (int k = 0; k < 16; ++k) s += mbuf[32 + k] * mw2[k * 8 + t];
    mbuf[48 + t] = fmaxf(s, 0.0f);
  }
  __syncthreads();
  if (t < 4) {
    float s = mb3[t];
    for (int k = 0; k < 8; ++k) s += mbuf[48 + k] * mw3[k * 4 + t];
    mbuf[56 + t] = fmaxf(s, 0.0f);
  }
  __syncthreads();
  if (t == 0) {
    float s = mb4[0];
    for (int k = 0; k < 4; ++k) s += mbuf[56 + k] * mw4[k];
    s = fmaxf(s, 0.0f);
    float z = s * sw[0] + sb[0];
    out[b] = 1.0f / (1.0f + expf(-z));
  }
}

extern "C" void kernel_launch(void* const* d_in, const int* in_sizes, int n_in,
                              void* d_out, int out_size, void* d_ws, size_t ws_size,
                              hipStream_t stream) {
  (void)in_sizes; (void)n_in; (void)out_size; (void)ws_size;
  const float* x_i = (const float*)d_in[0];
  const float* x_j = (const float*)d_in[1];
  const float* gw0 = (const float*)d_in[2];
  const float* gb0 = (const float*)d_in[3];
  const float* gw1 = (const float*)d_in[4];
  const float* gb1 = (const float*)d_in[5];
  const float* gw2 = (const float*)d_in[6];
  const float* gb2 = (const float*)d_in[7];
  const float* cw0 = (const float*)d_in[8];
  const float* cb0 = (const float*)d_in[9];
  const float* cw1 = (const float*)d_in[10];
  const float* cb1 = (const float*)d_in[11];
  const float* cw2 = (const float*)d_in[12];
  const float* cb2 = (const float*)d_in[13];
  const float* mw0 = (const float*)d_in[14];
  const float* mb0 = (const float*)d_in[15];
  const float* mw1 = (const float*)d_in[16];
  const float* mb1 = (const float*)d_in[17];
  const float* mw2 = (const float*)d_in[18];
  const float* mb2 = (const float*)d_in[19];
  const float* mw3 = (const float*)d_in[20];
  const float* mb3 = (const float*)d_in[21];
  const float* mw4 = (const float*)d_in[22];
  const float* mb4 = (const float*)d_in[23];
  const float* scw = (const float*)d_in[24];
  const float* scb = (const float*)d_in[25];
  const int* ei = (const int*)d_in[26];
  const int* ej = (const int*)d_in[27];
  float* out = (float*)d_out;

  char* p = (char*)d_ws;
  auto take = [&](size_t bytes) {
    char* r = p;
    p += (bytes + 255) & ~(size_t)255;
    return r;
  };
  float* hs0 = (float*)take((size_t)2 * BB * 20 * 64 * 4);
  float* hs1 = (float*)take((size_t)2 * BB * 20 * 32 * 4);
  float* hs2 = (float*)take((size_t)2 * BB * 20 * 16 * 4);

  k_all<<<2 * BB, 512, 0, stream>>>(x_i, x_j, gw0, gb0, gw1, gb1, gw2, gb2,
                                    ei, ej, hs0, hs1, hs2);
  k_head<<<BB, 256, 0, stream>>>(hs0, hs1, hs2, cw0, cb0, cw1, cb1, cw2, cb2,
                                 mw0, mb0, mw1, mb1, mw2, mb2, mw3, mb3, mw4, mb4,
                                 scw, scb, out);
}